// Round 12
// baseline (38519.699 us; speedup 1.0000x reference)
//
#include <hip/hip_runtime.h>
#include <cstdint>
#include <cstddef>

#define SEQ   8192
#define HD    2048
#define IND   16
#define NWRK  256   // worker blocks; each owns 8 hidden units
#define NRLY  8     // relay blocks (blockIdx 0..7)
#define NGRID (NWRK + NRLY)
#define NTHR  256   // 4 waves; wave w owns units {wid*8+2w, wid*8+2w+1}
#define NSLOT 1024  // u64 slots per parity: lo32 = 2xfp16 h-pair, hi32 = tag
#define NXCD  8

typedef _Float16 h2  __attribute__((ext_vector_type(2)));
typedef unsigned u32x4 __attribute__((ext_vector_type(4)));

union paircvt { h2 v; unsigned u; };

__device__ __forceinline__ float fdot2f(h2 a, h2 b, float c) {
#if defined(__has_builtin)
#if __has_builtin(__builtin_amdgcn_fdot2)
    return __builtin_amdgcn_fdot2(a, b, c, false);
#else
    return c + (float)a.x * (float)b.x + (float)a.y * (float)b.y;
#endif
#else
    return c + (float)a.x * (float)b.x + (float)a.y * (float)b.y;
#endif
}

__device__ __forceinline__ float sigmoid_f(float x) {
    return 1.f / (1.f + __expf(-x));
}
__device__ __forceinline__ float tanh_f(float x) {
    float e = __expf(2.f * x);
    return 1.f - 2.f / (e + 1.f);
}

__device__ __forceinline__ unsigned my_xcd() {
    unsigned x;
    asm volatile("s_getreg_b32 %0, hwreg(HW_REG_XCC_ID, 0, 4)" : "=s"(x));
    return x & (NXCD - 1);
}

// Persistent LSTM, round 12: R9 multicast + cleaned R8 relay.
// R9 (19.0 ms) still pays queueing: 32 blocks/replica x 8 KB sc1 polls per
// ~RT round inflate the IF round-trip. R11 proved same-wave vmcnt
// pipelining can't fix it (stores serialize the count). Here:
//   - producers multicast tagged 8B words to 8 per-XCD INBOXES (R9 path);
//   - relay blocks (blockIdx 0..7; serve whatever XCD they land on via
//     XCC_ID, duplicates harmless) hot-poll ONLY their inbox — 1 sc1
//     poller per region instead of 32 — and forward incrementally into a
//     MIRROR via explicit global_store_dwordx4 (local-L2 writeback);
//   - workers poll mirror[own_xcd] with sc0 (~200 cyc L2 RT); fallback
//     direct inbox sc1 read every 16th miss only (never fires in steady
//     state; guarantees no hang if a relay is missing — R7 lesson).
// Tags are embedded in every word: any hop, any staleness, acceptance is
// exact; transient old-value rewrites by lagging relays only delay.
// Compute path = R9 verbatim (absmax 2.44e-4, 0 conflicts, 1 barrier).
__global__ __launch_bounds__(NTHR, 1) void lstm_persist(
    const float* __restrict__ sa,    // [SEQ, IND]
    const float* __restrict__ W_ih,  // [4*HD, IND]
    const float* __restrict__ W_hh,  // [4*HD, HD]
    const float* __restrict__ b_ih,  // [4*HD]
    const float* __restrict__ b_hh,  // [4*HD]
    unsigned long long* __restrict__ inbox,  // [NXCD][2][NSLOT] (zeroed)
    unsigned long long* __restrict__ mirr,   // [NXCD][2][NSLOT] (zeroed)
    _Float16* __restrict__ hs16)     // [SEQ, HD] h history (fp16)
{
    const int tid = threadIdx.x;
    const int w   = tid >> 6;        // wave 0..3
    const int L   = tid & 63;        // lane
    const unsigned xcd = my_xcd();

    // ================= RELAY BLOCKS =================
    if (blockIdx.x < NRLY) {
        if (w != 0) return;          // one wave per relay
        for (unsigned t = 0; t < SEQ; ++t) {
            const unsigned pin = t & 1;
            const unsigned* gp0 =
                (const unsigned*)(inbox + ((size_t)xcd * 2 + pin) * NSLOT)
                + 4 * L;
            const unsigned* gp1 = gp0 + 1024;   // +4096 B
            unsigned* mb =
                (unsigned*)(mirr + ((size_t)xcd * 2 + pin) * NSLOT) + 4 * L;
            unsigned* mb1 = mb + 1024;
            for (;;) {
                u32x4 g0, g1, g2, g3, g4, g5, g6, g7;
                asm volatile(
                    "global_load_dwordx4 %0, %8, off sc1\n\t"
                    "global_load_dwordx4 %1, %8, off offset:1024 sc1\n\t"
                    "global_load_dwordx4 %2, %8, off offset:2048 sc1\n\t"
                    "global_load_dwordx4 %3, %8, off offset:3072 sc1\n\t"
                    "global_load_dwordx4 %4, %9, off sc1\n\t"
                    "global_load_dwordx4 %5, %9, off offset:1024 sc1\n\t"
                    "global_load_dwordx4 %6, %9, off offset:2048 sc1\n\t"
                    "global_load_dwordx4 %7, %9, off offset:3072 sc1\n\t"
                    "s_waitcnt vmcnt(0)"
                    : "=v"(g0), "=v"(g1), "=v"(g2), "=v"(g3),
                      "=v"(g4), "=v"(g5), "=v"(g6), "=v"(g7)
                    : "v"(gp0), "v"(gp1) : "memory");
                // incremental idempotent forward into own-XCD L2
                asm volatile(
                    "global_store_dwordx4 %0, %2, off\n\t"
                    "global_store_dwordx4 %0, %3, off offset:1024\n\t"
                    "global_store_dwordx4 %0, %4, off offset:2048\n\t"
                    "global_store_dwordx4 %0, %5, off offset:3072\n\t"
                    "global_store_dwordx4 %1, %6, off\n\t"
                    "global_store_dwordx4 %1, %7, off offset:1024\n\t"
                    "global_store_dwordx4 %1, %8, off offset:2048\n\t"
                    "global_store_dwordx4 %1, %9, off offset:3072"
                    :: "v"(mb), "v"(mb1),
                       "v"(g0), "v"(g1), "v"(g2), "v"(g3),
                       "v"(g4), "v"(g5), "v"(g6), "v"(g7) : "memory");
                bool ok = (g0.y == t) & (g0.w == t) & (g1.y == t) & (g1.w == t)
                        & (g2.y == t) & (g2.w == t) & (g3.y == t) & (g3.w == t)
                        & (g4.y == t) & (g4.w == t) & (g5.y == t) & (g5.w == t)
                        & (g6.y == t) & (g6.w == t) & (g7.y == t) & (g7.w == t);
                if (__all(ok)) break;
            }
        }
        return;
    }

    // ================= WORKER BLOCKS (R9 core) =================
    const int wid = blockIdx.x - NRLY;   // 0..255
    __shared__ h2 hh2[16 * 64];          // h_t pairs, XOR-swizzled

    const int ubase = wid * 8 + 2 * w;   // first of this wave's 2 units

    // ---- one-time: W_hh fragment -> registers (fp16 pairs) ----
    h2 wreg[8][16];
#pragma unroll
    for (int r = 0; r < 8; ++r) {
        const int row = (r & 3) * HD + ubase + (r >> 2);
        const float4* Wr = (const float4*)(W_hh + (size_t)row * HD + L * 32);
#pragma unroll
        for (int q = 0; q < 8; ++q) {
            float4 f = Wr[q];
            h2 lo; lo.x = (_Float16)f.x; lo.y = (_Float16)f.y;
            h2 hi; hi.x = (_Float16)f.z; hi.y = (_Float16)f.w;
            wreg[r][2 * q]     = lo;
            wreg[r][2 * q + 1] = hi;
        }
    }
    const int rowL = (L & 3) * HD + ubase + ((L >> 2) & 1);
    float wih[IND];
    {
        const float4* Wi = (const float4*)(W_ih + (size_t)rowL * IND);
#pragma unroll
        for (int q = 0; q < 4; ++q) {
            float4 f = Wi[q];
            wih[4 * q]     = f.x;
            wih[4 * q + 1] = f.y;
            wih[4 * q + 2] = f.z;
            wih[4 * q + 3] = f.w;
        }
    }
    const float bias = b_ih[rowL] + b_hh[rowL];

    float c = 0.f;   // (L&4)==0 -> unit0, else unit1

    for (unsigned t = 0; t < SEQ; ++t) {
        // ---- xp precompute (h-independent): hidden under the poll ----
        float xp = bias;
        {
            const float* sat = sa + (size_t)t * IND;
#pragma unroll
            for (int k = 0; k < IND; ++k) xp += sat[k] * wih[k];
        }

        // ---- poll own-XCD mirror (sc0, local L2); rare sc1 fallback ----
        const unsigned pin = t & 1;
        const uint32_t* mbase =
            (const uint32_t*)(mirr + ((size_t)xcd * 2 + pin) * NSLOT);
        const uint32_t* mp0 = mbase + 4 * tid;
        const uint32_t* mp1 = mbase + 1024 + 4 * tid;
        const uint32_t* ibase =
            (const uint32_t*)(inbox + ((size_t)xcd * 2 + pin) * NSLOT);
        const uint32_t* ip0 = ibase + 4 * tid;
        const uint32_t* ip1 = ibase + 1024 + 4 * tid;
        u32x4 m0, m1;
        unsigned miss = 0;
        for (;;) {
            asm volatile(
                "global_load_dwordx4 %0, %2, off sc0\n\t"
                "global_load_dwordx4 %1, %3, off sc0\n\t"
                "s_waitcnt vmcnt(0)"
                : "=v"(m0), "=v"(m1)
                : "v"(mp0), "v"(mp1) : "memory");
            if ((m0.y == t) & (m0.w == t) & (m1.y == t) & (m1.w == t)) break;
            if ((++miss & 15u) == 0u) {
                asm volatile(
                    "global_load_dwordx4 %0, %2, off sc1\n\t"
                    "global_load_dwordx4 %1, %3, off sc1\n\t"
                    "s_waitcnt vmcnt(0)"
                    : "=v"(m0), "=v"(m1)
                    : "v"(ip0), "v"(ip1) : "memory");
                if ((m0.y == t) & (m0.w == t) & (m1.y == t) & (m1.w == t))
                    break;
            }
            __builtin_amdgcn_s_sleep(1);
        }

        // ---- stage 4 pairs into swizzled LDS (<=2-way = free) ----
        {
            paircvt cv;
            const int pa = 2 * tid, pb = 2 * tid + 1;
            const int pc = 512 + 2 * tid, pd = 513 + 2 * tid;
            cv.u = m0.x;
            hh2[(pa & 15) * 64 + (((pa >> 4) ^ (2 * (pa & 15))) & 63)] = cv.v;
            cv.u = m0.z;
            hh2[(pb & 15) * 64 + (((pb >> 4) ^ (2 * (pb & 15))) & 63)] = cv.v;
            cv.u = m1.x;
            hh2[(pc & 15) * 64 + (((pc >> 4) ^ (2 * (pc & 15))) & 63)] = cv.v;
            cv.u = m1.z;
            hh2[(pd & 15) * 64 + (((pd >> 4) ^ (2 * (pd & 15))) & 63)] = cv.v;
        }
        __syncthreads();

        // ---- read this lane's 16 pairs (cols [32L, 32L+32)) ----
        h2 hv[16];
#pragma unroll
        for (int k = 0; k < 16; ++k)
            hv[k] = hh2[k * 64 + ((L ^ (2 * k)) & 63)];

        // ---- 8 rows x 32 cols of dot product per lane ----
        float p[8] = {0.f, 0.f, 0.f, 0.f, 0.f, 0.f, 0.f, 0.f};
#pragma unroll
        for (int r = 0; r < 8; ++r)
#pragma unroll
            for (int k = 0; k < 16; ++k)
                p[r] = fdot2f(wreg[r][k], hv[k], p[r]);

        // ---- merge-reduce: lane L ends with full sum of row (L&7) ----
        const bool h1 = (L & 1), h2b = (L & 2), h4 = (L & 4);
        float v0, v1, v2, v3;
        {
            float k0 = h1 ? p[1] : p[0], s0 = h1 ? p[0] : p[1];
            v0 = k0 + __shfl_xor(s0, 1, 64);
            float k1 = h1 ? p[3] : p[2], s1 = h1 ? p[2] : p[3];
            v1 = k1 + __shfl_xor(s1, 1, 64);
            float k2 = h1 ? p[5] : p[4], s2 = h1 ? p[4] : p[5];
            v2 = k2 + __shfl_xor(s2, 1, 64);
            float k3 = h1 ? p[7] : p[6], s3 = h1 ? p[6] : p[7];
            v3 = k3 + __shfl_xor(s3, 1, 64);
        }
        float w0, w1;
        {
            float k0 = h2b ? v1 : v0, s0 = h2b ? v0 : v1;
            w0 = k0 + __shfl_xor(s0, 2, 64);
            float k1 = h2b ? v3 : v2, s1 = h2b ? v2 : v3;
            w1 = k1 + __shfl_xor(s1, 2, 64);
        }
        float tot;
        {
            float k0 = h4 ? w1 : w0, s0 = h4 ? w0 : w1;
            tot = k0 + __shfl_xor(s0, 4, 64);
        }
        tot += __shfl_xor(tot, 8, 64);
        tot += __shfl_xor(tot, 16, 64);
        tot += __shfl_xor(tot, 32, 64);
        tot += xp;

        // ---- gates: all intra-wave (width-8 shuffles) ----
        const int ub4 = L & 4;
        float gi = __shfl(tot, ub4 + 0, 8);
        float gf = __shfl(tot, ub4 + 1, 8);
        float gg = __shfl(tot, ub4 + 2, 8);
        float go = __shfl(tot, ub4 + 3, 8);
        float ii = sigmoid_f(gi);
        float ff = sigmoid_f(gf);
        float g  = tanh_f(gg);
        float oo = sigmoid_f(go);
        c = ff * c + ii * g;
        float h = oo * tanh_f(c);
        float hO = __shfl_xor(h, 4, 64);

        // ---- publish: multicast tagged word to all 8 inboxes ----
        if (L == 0) {
            paircvt pk;
            pk.v.x = (_Float16)h;
            pk.v.y = (_Float16)hO;
            ((unsigned*)hs16)[(size_t)t * (HD / 2) + wid * 4 + w] = pk.u;
            const unsigned pout = (t + 1) & 1;
            const size_t slot = (size_t)wid * 4 + w;
            unsigned long long msg =
                ((unsigned long long)(t + 1) << 32) | (unsigned long long)pk.u;
#pragma unroll
            for (int x = 0; x < NXCD; ++x)
                __hip_atomic_store(
                    &inbox[((size_t)x * 2 + pout) * NSLOT + slot], msg,
                    __ATOMIC_RELAXED, __HIP_MEMORY_SCOPE_AGENT);
        }
    }
}

// Output projection: out[t,0:3] = hs[t]·W_uvw^T + b_uvw,
//                    out[t,3:6] = hs[t]·W_pqr^T + b_pqr
__global__ __launch_bounds__(256) void out_proj_kernel(
    const _Float16* __restrict__ hs16,
    const float* __restrict__ W_uvw, const float* __restrict__ b_uvw,
    const float* __restrict__ W_pqr, const float* __restrict__ b_pqr,
    float* __restrict__ out)
{
    __shared__ float Ws[6 * HD];
    const int tid = threadIdx.x;
    for (int i = tid; i < 3 * HD; i += 256) Ws[i] = W_uvw[i];
    for (int i = tid; i < 3 * HD; i += 256) Ws[3 * HD + i] = W_pqr[i];
    __syncthreads();

    const int w = tid >> 6, L = tid & 63;
#pragma unroll
    for (int r = 0; r < 4; ++r) {
        const int t = blockIdx.x * 16 + w * 4 + r;
        const _Float16* hrow = hs16 + (size_t)t * HD;
        float acc[6] = {0.f, 0.f, 0.f, 0.f, 0.f, 0.f};
        for (int cidx = L; cidx < HD; cidx += 64) {
            float hval = (float)hrow[cidx];
#pragma unroll
            for (int j = 0; j < 6; ++j) acc[j] += hval * Ws[j * HD + cidx];
        }
#pragma unroll
        for (int j = 0; j < 6; ++j) {
#pragma unroll
            for (int d = 1; d < 64; d <<= 1)
                acc[j] += __shfl_xor(acc[j], d, 64);
        }
        if (L == 0) {
#pragma unroll
            for (int j = 0; j < 6; ++j)
                out[(size_t)t * 6 + j] =
                    acc[j] + (j < 3 ? b_uvw[j] : b_pqr[j - 3]);
        }
    }
}

extern "C" void kernel_launch(void* const* d_in, const int* in_sizes, int n_in,
                              void* d_out, int out_size, void* d_ws, size_t ws_size,
                              hipStream_t stream) {
    (void)in_sizes; (void)n_in; (void)out_size; (void)ws_size;

    const float* sa    = (const float*)d_in[0];
    const float* W_ih  = (const float*)d_in[1];
    const float* W_hh  = (const float*)d_in[2];
    const float* b_ih  = (const float*)d_in[3];
    const float* b_hh  = (const float*)d_in[4];
    const float* W_uvw = (const float*)d_in[5];
    const float* b_uvw = (const float*)d_in[6];
    const float* W_pqr = (const float*)d_in[7];
    const float* b_pqr = (const float*)d_in[8];
    float* out = (float*)d_out;

    // workspace: [hs16: 32 MB][inbox: 128 KB][mirr: 128 KB]
    char* ws = (char*)d_ws;
    _Float16* hs16 = (_Float16*)ws;
    unsigned long long* inbox =
        (unsigned long long*)(ws + (size_t)SEQ * HD * 2);
    unsigned long long* mirr = inbox + (size_t)NXCD * 2 * NSLOT;

    // zero inboxes + mirrors: tag 0 == "h_0 = 0 is ready" everywhere
    hipMemsetAsync(inbox, 0, (size_t)2 * NXCD * 2 * NSLOT * 8, stream);

    hipLaunchKernelGGL(lstm_persist, dim3(NGRID), dim3(NTHR), 0, stream,
                       sa, W_ih, W_hh, b_ih, b_hh, inbox, mirr, hs16);
    hipLaunchKernelGGL(out_proj_kernel, dim3(SEQ / 16), dim3(256), 0, stream,
                       hs16, W_uvw, b_uvw, W_pqr, b_pqr, out);
}

// Round 13
// 26652.243 us; speedup vs baseline: 1.4453x; 1.4453x over previous
//
#include <hip/hip_runtime.h>
#include <cstdint>
#include <cstddef>

#define SEQ   8192
#define HD    2048
#define IND   16
#define NBLK  256   // one block per CU; each owns 8 hidden units
#define NTHR  256   // 4 waves; wave w owns units {b*8+2w, b*8+2w+1} = 8 rows
#define NSLOT 1024  // u64 slots per parity: lo32 = 2xfp16 h-pair, hi32 = tag
#define NXCD  8

typedef _Float16 h2  __attribute__((ext_vector_type(2)));
typedef unsigned u32x4 __attribute__((ext_vector_type(4)));

union paircvt { h2 v; unsigned u; };

__device__ __forceinline__ float fdot2f(h2 a, h2 b, float c) {
#if defined(__has_builtin)
#if __has_builtin(__builtin_amdgcn_fdot2)
    return __builtin_amdgcn_fdot2(a, b, c, false);
#else
    return c + (float)a.x * (float)b.x + (float)a.y * (float)b.y;
#endif
#else
    return c + (float)a.x * (float)b.x + (float)a.y * (float)b.y;
#endif
}

__device__ __forceinline__ float sigmoid_f(float x) {
    return 1.f / (1.f + __expf(-x));
}
__device__ __forceinline__ float tanh_f(float x) {
    float e = __expf(2.f * x);
    return 1.f - 2.f / (e + 1.f);
}

__device__ __forceinline__ unsigned my_xcd() {
    unsigned x;
    asm volatile("s_getreg_b32 %0, hwreg(HW_REG_XCC_ID, 0, 4)" : "=s"(x));
    return x & (NXCD - 1);
}

// Persistent LSTM, round 13: R9 (best, 19.0 ms) + two targeted fixes.
// Relay topologies lose every time (R6/R10/R12): any serial forwarding hop
// adds its own detection latency to all consumers. Flat 8x-replica
// multicast stands. Fixes here:
//  (1) PREDICATED RE-POLLING: after the first full round, only lanes with
//      missing tags re-issue their 16B load (exec-masked). Steady-state
//      poll traffic drops ~5-10x -> less queueing on the polled lines
//      (R11 showed RT is traffic-sensitive).
//  (2) SINGLE-INSTRUCTION MULTICAST PUBLISH: lanes 0..7 each store the
//      same tagged 8B word to replica L in ONE exec-masked store (R9 used
//      8 serial stores whose acks the next poll's vmcnt(0) drained).
// Compute path = R9 verbatim (absmax 2.44e-4, 0 LDS conflicts, 1 barrier).
__global__ __launch_bounds__(NTHR, 1) void lstm_persist(
    const float* __restrict__ sa,    // [SEQ, IND]
    const float* __restrict__ W_ih,  // [4*HD, IND]
    const float* __restrict__ W_hh,  // [4*HD, HD]
    const float* __restrict__ b_ih,  // [4*HD]
    const float* __restrict__ b_hh,  // [4*HD]
    unsigned long long* __restrict__ hrep,  // [NXCD][2][NSLOT] replicas
    _Float16* __restrict__ hs16)     // [SEQ, HD] h history (fp16)
{
    const int b   = blockIdx.x;
    const int tid = threadIdx.x;
    const int w   = tid >> 6;        // wave 0..3
    const int L   = tid & 63;        // lane
    const unsigned xcd = my_xcd();

    __shared__ h2 hh2[16 * 64];      // h_t pairs, XOR-swizzled [k][row^2k]

    const int ubase = b * 8 + 2 * w; // first of this wave's 2 units

    // ---- one-time: W_hh fragment -> registers (fp16 pairs) ----
    // 8 rows (r: gate=r&3, unit=r>>2), lane L owns cols [32L, 32L+32)
    h2 wreg[8][16];
#pragma unroll
    for (int r = 0; r < 8; ++r) {
        const int row = (r & 3) * HD + ubase + (r >> 2);
        const float4* Wr = (const float4*)(W_hh + (size_t)row * HD + L * 32);
#pragma unroll
        for (int q = 0; q < 8; ++q) {
            float4 f = Wr[q];
            h2 lo; lo.x = (_Float16)f.x; lo.y = (_Float16)f.y;
            h2 hi; hi.x = (_Float16)f.z; hi.y = (_Float16)f.w;
            wreg[r][2 * q]     = lo;
            wreg[r][2 * q + 1] = hi;
        }
    }
    // W_ih row + bias for the row this lane ends up holding (r = L&7)
    const int rowL = (L & 3) * HD + ubase + ((L >> 2) & 1);
    float wih[IND];
    {
        const float4* Wi = (const float4*)(W_ih + (size_t)rowL * IND);
#pragma unroll
        for (int q = 0; q < 4; ++q) {
            float4 f = Wi[q];
            wih[4 * q]     = f.x;
            wih[4 * q + 1] = f.y;
            wih[4 * q + 2] = f.z;
            wih[4 * q + 3] = f.w;
        }
    }
    const float bias = b_ih[rowL] + b_hh[rowL];

    // cell state: lanes with (L&4)==0 hold c of unit0, (L&4)==4 -> unit1
    float c = 0.f;

    for (unsigned t = 0; t < SEQ; ++t) {
        // ---- xp precompute (h-independent): hidden under the poll ----
        float xp = bias;
        {
            const float* sat = sa + (size_t)t * IND;
#pragma unroll
            for (int k = 0; k < IND; ++k) xp += sat[k] * wih[k];
        }

        // ---- poll own-XCD replica: first full round, then PREDICATED
        //      per-lane re-polls (only missing lanes issue traffic) ----
        const unsigned pin = t & 1;
        const uint32_t* base =
            (const uint32_t*)(hrep + ((size_t)xcd * 2 + pin) * NSLOT);
        const uint32_t* pp0 = base + 4 * tid;
        const uint32_t* pp1 = base + 1024 + 4 * tid;
        u32x4 m0, m1;
        asm volatile(
            "global_load_dwordx4 %0, %2, off sc1\n\t"
            "global_load_dwordx4 %1, %3, off sc1\n\t"
            "s_waitcnt vmcnt(0)"
            : "=v"(m0), "=v"(m1)
            : "v"(pp0), "v"(pp1) : "memory");
        bool ok0 = (m0.y == t) & (m0.w == t);
        bool ok1 = (m1.y == t) & (m1.w == t);
        while (!__all((int)(ok0 & ok1))) {
            __builtin_amdgcn_s_sleep(1);
            if (!ok0) {
                u32x4 r;
                asm volatile("global_load_dwordx4 %0, %1, off sc1"
                             : "=v"(r) : "v"(pp0) : "memory");
                asm volatile("s_waitcnt vmcnt(0)" ::: "memory");
                m0 = r;
            }
            if (!ok1) {
                u32x4 r;
                asm volatile("global_load_dwordx4 %0, %1, off sc1"
                             : "=v"(r) : "v"(pp1) : "memory");
                asm volatile("s_waitcnt vmcnt(0)" ::: "memory");
                m1 = r;
            }
            ok0 = (m0.y == t) & (m0.w == t);
            ok1 = (m1.y == t) & (m1.w == t);
        }

        // ---- stage 4 pairs into swizzled LDS (<=2-way = free) ----
        {
            paircvt cv;
            const int pa = 2 * tid, pb = 2 * tid + 1;
            const int pc = 512 + 2 * tid, pd = 513 + 2 * tid;
            cv.u = m0.x;
            hh2[(pa & 15) * 64 + (((pa >> 4) ^ (2 * (pa & 15))) & 63)] = cv.v;
            cv.u = m0.z;
            hh2[(pb & 15) * 64 + (((pb >> 4) ^ (2 * (pb & 15))) & 63)] = cv.v;
            cv.u = m1.x;
            hh2[(pc & 15) * 64 + (((pc >> 4) ^ (2 * (pc & 15))) & 63)] = cv.v;
            cv.u = m1.z;
            hh2[(pd & 15) * 64 + (((pd >> 4) ^ (2 * (pd & 15))) & 63)] = cv.v;
        }
        __syncthreads();

        // ---- read this lane's 16 pairs (cols [32L, 32L+32)) ----
        h2 hv[16];
#pragma unroll
        for (int k = 0; k < 16; ++k)
            hv[k] = hh2[k * 64 + ((L ^ (2 * k)) & 63)];

        // ---- 8 rows x 32 cols of dot product per lane ----
        float p[8] = {0.f, 0.f, 0.f, 0.f, 0.f, 0.f, 0.f, 0.f};
#pragma unroll
        for (int r = 0; r < 8; ++r)
#pragma unroll
            for (int k = 0; k < 16; ++k)
                p[r] = fdot2f(wreg[r][k], hv[k], p[r]);

        // ---- merge-reduce: lane L ends with full sum of row (L&7) ----
        const bool h1 = (L & 1), h2b = (L & 2), h4 = (L & 4);
        float v0, v1, v2, v3;
        {
            float k0 = h1 ? p[1] : p[0], s0 = h1 ? p[0] : p[1];
            v0 = k0 + __shfl_xor(s0, 1, 64);
            float k1 = h1 ? p[3] : p[2], s1 = h1 ? p[2] : p[3];
            v1 = k1 + __shfl_xor(s1, 1, 64);
            float k2 = h1 ? p[5] : p[4], s2 = h1 ? p[4] : p[5];
            v2 = k2 + __shfl_xor(s2, 1, 64);
            float k3 = h1 ? p[7] : p[6], s3 = h1 ? p[6] : p[7];
            v3 = k3 + __shfl_xor(s3, 1, 64);
        }
        float w0, w1;
        {
            float k0 = h2b ? v1 : v0, s0 = h2b ? v0 : v1;
            w0 = k0 + __shfl_xor(s0, 2, 64);
            float k1 = h2b ? v3 : v2, s1 = h2b ? v2 : v3;
            w1 = k1 + __shfl_xor(s1, 2, 64);
        }
        float tot;
        {
            float k0 = h4 ? w1 : w0, s0 = h4 ? w0 : w1;
            tot = k0 + __shfl_xor(s0, 4, 64);
        }
        tot += __shfl_xor(tot, 8, 64);
        tot += __shfl_xor(tot, 16, 64);
        tot += __shfl_xor(tot, 32, 64);
        tot += xp;

        // ---- gates: all intra-wave (width-8 shuffles) ----
        const int ub4 = L & 4;   // 0 -> unit0 rows 0..3, 4 -> unit1 rows 4..7
        float gi = __shfl(tot, ub4 + 0, 8);
        float gf = __shfl(tot, ub4 + 1, 8);
        float gg = __shfl(tot, ub4 + 2, 8);
        float go = __shfl(tot, ub4 + 3, 8);
        float ii = sigmoid_f(gi);
        float ff = sigmoid_f(gf);
        float g  = tanh_f(gg);
        float oo = sigmoid_f(go);
        c = ff * c + ii * g;
        float h = oo * tanh_f(c);
        float hO = __shfl_xor(h, 4, 64);   // partner unit's h

        // ---- publish: ONE exec-masked store, lanes 0..7 -> replica L ----
        {
            // all lanes build the canonical (unit0, unit1) packed word
            float hu0 = (L & 4) ? hO : h;
            float hu1 = (L & 4) ? h : hO;
            paircvt pk;
            pk.v.x = (_Float16)hu0;
            pk.v.y = (_Float16)hu1;
            const unsigned pout = (t + 1) & 1;
            const size_t slot = (size_t)b * 4 + w;
            unsigned long long msg =
                ((unsigned long long)(t + 1) << 32) | (unsigned long long)pk.u;
            if (L == 0)
                ((unsigned*)hs16)[(size_t)t * (HD / 2) + slot] = pk.u;
            if (L < NXCD)
                __hip_atomic_store(
                    &hrep[((size_t)L * 2 + pout) * NSLOT + slot], msg,
                    __ATOMIC_RELAXED, __HIP_MEMORY_SCOPE_AGENT);
        }
    }
}

// Output projection: out[t,0:3] = hs[t]·W_uvw^T + b_uvw,
//                    out[t,3:6] = hs[t]·W_pqr^T + b_pqr
__global__ __launch_bounds__(256) void out_proj_kernel(
    const _Float16* __restrict__ hs16,
    const float* __restrict__ W_uvw, const float* __restrict__ b_uvw,
    const float* __restrict__ W_pqr, const float* __restrict__ b_pqr,
    float* __restrict__ out)
{
    __shared__ float Ws[6 * HD];
    const int tid = threadIdx.x;
    for (int i = tid; i < 3 * HD; i += 256) Ws[i] = W_uvw[i];
    for (int i = tid; i < 3 * HD; i += 256) Ws[3 * HD + i] = W_pqr[i];
    __syncthreads();

    const int w = tid >> 6, L = tid & 63;
#pragma unroll
    for (int r = 0; r < 4; ++r) {
        const int t = blockIdx.x * 16 + w * 4 + r;
        const _Float16* hrow = hs16 + (size_t)t * HD;
        float acc[6] = {0.f, 0.f, 0.f, 0.f, 0.f, 0.f};
        for (int cidx = L; cidx < HD; cidx += 64) {
            float hval = (float)hrow[cidx];
#pragma unroll
            for (int j = 0; j < 6; ++j) acc[j] += hval * Ws[j * HD + cidx];
        }
#pragma unroll
        for (int j = 0; j < 6; ++j) {
#pragma unroll
            for (int d = 1; d < 64; d <<= 1)
                acc[j] += __shfl_xor(acc[j], d, 64);
        }
        if (L == 0) {
#pragma unroll
            for (int j = 0; j < 6; ++j)
                out[(size_t)t * 6 + j] =
                    acc[j] + (j < 3 ? b_uvw[j] : b_pqr[j - 3]);
        }
    }
}

extern "C" void kernel_launch(void* const* d_in, const int* in_sizes, int n_in,
                              void* d_out, int out_size, void* d_ws, size_t ws_size,
                              hipStream_t stream) {
    (void)in_sizes; (void)n_in; (void)out_size; (void)ws_size;

    const float* sa    = (const float*)d_in[0];
    const float* W_ih  = (const float*)d_in[1];
    const float* W_hh  = (const float*)d_in[2];
    const float* b_ih  = (const float*)d_in[3];
    const float* b_hh  = (const float*)d_in[4];
    const float* W_uvw = (const float*)d_in[5];
    const float* b_uvw = (const float*)d_in[6];
    const float* W_pqr = (const float*)d_in[7];
    const float* b_pqr = (const float*)d_in[8];
    float* out = (float*)d_out;

    // workspace: [hs16: 32 MB][hrep: NXCD*2*NSLOT*8 = 128 KB]
    char* ws = (char*)d_ws;
    _Float16* hs16 = (_Float16*)ws;
    unsigned long long* hrep =
        (unsigned long long*)(ws + (size_t)SEQ * HD * 2);

    // zero replicas: tag 0 == "h_0 = 0 is ready" in every copy
    hipMemsetAsync(hrep, 0, (size_t)NXCD * 2 * NSLOT * 8, stream);

    hipLaunchKernelGGL(lstm_persist, dim3(NBLK), dim3(NTHR), 0, stream,
                       sa, W_ih, W_hh, b_ih, b_hh, hrep, hs16);
    hipLaunchKernelGGL(out_proj_kernel, dim3(SEQ / 16), dim3(256), 0, stream,
                       hs16, W_uvw, b_uvw, W_pqr, b_pqr, out);
}